// Round 8
// baseline (1100.540 us; speedup 1.0000x reference)
//
#include <hip/hip_runtime.h>
#include <hip/hip_bf16.h>
#include <stdint.h>

static constexpr int kL  = 5;
static constexpr int kNH = 4;
static constexpr int kP  = 4;
static constexpr int kE  = 256;
static constexpr int kC  = 256;
static constexpr int kH  = 128;
static constexpr int kW  = 128;
static constexpr int kNQ = kH * kW;          // 16384
static constexpr int kNL = 6;
static constexpr int kFF = 2 * kE;           // 512
static constexpr int kCOMB = 240;            // 160 off + 80 aw (stored ld 256)

typedef short bf16x8 __attribute__((ext_vector_type(8)));
typedef float f32x4 __attribute__((ext_vector_type(4)));

__device__ __forceinline__ short f2bf(float x) {
  union { float f; uint32_t u; } v; v.f = x;
  uint32_t r = v.u + 0x7fffu + ((v.u >> 16) & 1u);
  return (short)(r >> 16);
}
__device__ __forceinline__ uint32_t pack2(float a, float b) {
  return (uint32_t)(unsigned short)f2bf(a) | ((uint32_t)(unsigned short)f2bf(b) << 16);
}
__device__ __forceinline__ float bflo(uint32_t u) { return __uint_as_float(u << 16); }
__device__ __forceinline__ float bfhi(uint32_t u) { return __uint_as_float(u & 0xffff0000u); }
__device__ __forceinline__ float bf2f(unsigned short u) {
  return __uint_as_float((uint32_t)u << 16);
}

__device__ __forceinline__ void gl_lds16(const void* g, void* l) {
  __builtin_amdgcn_global_load_lds(
      (const __attribute__((address_space(1))) void*)g,
      (__attribute__((address_space(3))) void*)l, 16, 0, 0);
}

// ---------------------------------------------------------------------------
// LDS-staged bf16 MFMA GEMM, 512 threads (8 waves, 2Mx4N), BM=64, BN=256,
// 2-phase double-buffered pipeline (STAGE(t+1) before compute(t), one
// barrier per tile). Staging unit = 1KB group (16 rows x 32 k),
// pre-swizzled source (skof) + swizzled fragment read (ua).
// MODE 0: BK=64 (LDS 80KB, 2 blocks/CU). bias (+relu) -> Cf and/or Cb
//         (z encoded via blockIdx.x: col0 selects weight slab, zouts strides Cb)
// MODE 5: BK=32 (LDS 75KB, 2 blocks/CU). v=acc+bias -> Cf fp32 (q);
//         qpS = bf16(v+pos); fused comb GEMM2 (inproj + layer-0 comb)
// ---------------------------------------------------------------------------
template <int BM, int MODE, int RB>
__global__ __launch_bounds__(512, 4) void gemm2_kernel(
    const short* __restrict__ A, long sAb, int lda,
    const short* __restrict__ BT, int ldbt, int Kb, int nbatch,
    const float* __restrict__ bias,
    float* Cf, short* __restrict__ Cb, int ldc, int relu, long zouts,
    const float* __restrict__ pos_row, const float* __restrict__ pos_col,
    const short* __restrict__ w2BT, const float* __restrict__ w2B,
    short* __restrict__ out2) {
  static_assert(BM == 64, "layout assumes BM=64");
  constexpr bool FUSED = (MODE == 5);
  constexpr int BK = FUSED ? 32 : 64;
  constexpr int KG = BK / 32;
  constexpr int NW = 8;
  constexpr int MT = 2;
  constexpr int NT = 4;
  constexpr int AG = (BM / 16) * KG;
  constexpr int BG = 16 * KG;
  constexpr int ASZ = BM * BK;
  constexpr int BSZ = 256 * BK;
  __shared__ short smem[2 * ASZ + 2 * BSZ + (FUSED ? 64 * 280 : 0)];
  short* const Asm = smem;
  short* const Bsm = smem + 2 * ASZ;
  short* const qpS = smem + 2 * ASZ + 2 * BSZ;          // FUSED only
  const int tid = threadIdx.x;
  const int wave = tid >> 6, lane = tid & 63;
  const int wy = wave >> 2, wx = wave & 3;
  const long row0 = (long)blockIdx.y * BM;
  const int col0 = blockIdx.x * 256;
  const int srow = lane >> 2;
  const int skof = ((lane & 3) ^ (srow & 3)) * 8;
  const int fr = lane & 15, fq = lane >> 4;
  const int ua = (fr * 4 + (fq ^ (fr & 3))) * 8;
  f32x4 acc[MT][NT] = {};
  const int KT = Kb / BK;
  const int NTILES = nbatch * KT;

  auto stage_tile = [&](int buf, int bb, int kt) {
    const short* Ab = A + (long)bb * sAb + row0 * lda;
    const short* Bb = BT + (long)col0 * ldbt + (long)bb * Kb;
    int k0 = kt * BK;
#pragma unroll
    for (int t = wave; t < AG + BG; t += NW) {
      if (t < AG) {
        int rg = t / KG, kg = t % KG;
        gl_lds16(Ab + (long)(rg * 16 + srow) * lda + k0 + kg * 32 + skof,
                 &Asm[buf * ASZ + t * 512]);
      } else {
        int u = t - AG;
        int rg = u / KG, kg = u % KG;
        gl_lds16(Bb + (long)(rg * 16 + srow) * ldbt + k0 + kg * 32 + skof,
                 &Bsm[buf * BSZ + u * 512]);
      }
    }
  };

  int cur = 0;
  stage_tile(0, 0, 0);
  __syncthreads();
  int sb = 0, sk = 0;
  for (int idx = 0; idx < NTILES; ++idx) {
    if (idx + 1 < NTILES) {
      if (++sk == KT) { sk = 0; ++sb; }
      stage_tile(cur ^ 1, sb, sk);
    }
#pragma unroll
    for (int kk = 0; kk < KG; ++kk) {
      bf16x8 af[MT], bfv[NT];
#pragma unroll
      for (int t = 0; t < MT; ++t)
        af[t] = *(const bf16x8*)&Asm[cur * ASZ + ((wy * MT + t) * KG + kk) * 512 + ua];
#pragma unroll
      for (int t = 0; t < NT; ++t)
        bfv[t] = *(const bf16x8*)&Bsm[cur * BSZ + ((wx * 4 + t) * KG + kk) * 512 + ua];
#pragma unroll
      for (int mt = 0; mt < MT; ++mt)
#pragma unroll
        for (int nt = 0; nt < NT; ++nt)
          acc[mt][nt] = __builtin_amdgcn_mfma_f32_16x16x32_bf16(
              af[mt], bfv[nt], acc[mt][nt], 0, 0, 0);
    }
    __syncthreads();
    cur ^= 1;
  }

  const int colb = col0 + wx * 64 + fr;            // + nt*16
  const long rowb = row0 + wy * 32 + fq * 4;       // + mt*16 + rr

  if (MODE == 0) {
    const long zoff = (long)blockIdx.x * zouts;
#pragma unroll
    for (int mt = 0; mt < MT; ++mt)
#pragma unroll
      for (int rr = 0; rr < 4; ++rr) {
        long row = rowb + mt * 16 + rr;
#pragma unroll
        for (int nt = 0; nt < NT; ++nt) {
          int col = colb + nt * 16;
          float v = acc[mt][nt][rr] + bias[col];
          if (relu) v = fmaxf(v, 0.f);
          if (Cf) Cf[row * ldc + col] = v;
          if (Cb) Cb[zoff + row * ldc + col] = f2bf(v);
        }
      }
  } else if (MODE == 5) {
#pragma unroll
    for (int mt = 0; mt < MT; ++mt)
#pragma unroll
      for (int rr = 0; rr < 4; ++rr) {
        long row = rowb + mt * 16 + rr;
        int rl = wy * 32 + mt * 16 + fq * 4 + rr;
        int wpos = (int)row & (kW - 1), hpos = (int)row >> 7;
#pragma unroll
        for (int nt = 0; nt < NT; ++nt) {
          int col = colb + nt * 16;
          float v = acc[mt][nt][rr] + bias[col];
          Cf[row * 256 + col] = v;
          float pv = (col < 128) ? pos_col[wpos * 128 + col]
                                 : pos_row[hpos * 128 + (col - 128)];
          qpS[rl * 280 + col] = f2bf(v + pv);
        }
      }
  }
  if constexpr (FUSED) {
    // fused comb GEMM2: out2 = qpS @ w2BT^T + w2B   (K=256, 8 BK=32 tiles)
    auto stageW = [&](int buf, int t2) {
      int k0 = t2 * BK;
#pragma unroll
      for (int u = wave; u < BG; u += NW) {
        gl_lds16(w2BT + (long)(u * 16 + srow) * 256 + k0 + skof,
                 &Bsm[buf * BSZ + u * 512]);
      }
    };
    f32x4 acc2[4][NT] = {};
    stageW(cur, 0);
    __syncthreads();
    for (int t2 = 0; t2 < 8; ++t2) {
      if (t2 + 1 < 8) stageW(cur ^ 1, t2 + 1);
      int k0 = t2 * BK;
#pragma unroll
      for (int mt = 0; mt < 4; ++mt) {
        bf16x8 av = *(const bf16x8*)&qpS[(mt * 16 + fr) * 280 + k0 + fq * 8];
#pragma unroll
        for (int t = 0; t < NT; ++t) {
          bf16x8 bv = *(const bf16x8*)&Bsm[cur * BSZ + (wx * 4 + t) * 512 + ua];
          acc2[mt][t] = __builtin_amdgcn_mfma_f32_16x16x32_bf16(
              av, bv, acc2[mt][t], 0, 0, 0);
        }
      }
      __syncthreads();
      cur ^= 1;
    }
#pragma unroll
    for (int mt = 0; mt < 4; ++mt)
#pragma unroll
      for (int rr = 0; rr < 4; ++rr) {
        long row = row0 + mt * 16 + fq * 4 + rr;
#pragma unroll
        for (int nt = 0; nt < NT; ++nt) {
          int oc = wx * 64 + nt * 16 + fr;
          out2[row * 256 + oc] = f2bf(acc2[mt][nt][rr] + w2B[oc]);
        }
      }
  }
}

// ---------------------------------------------------------------------------
// Full-layer fused kernel: out-proj + resid + LN1 + FFN1 + FFN2 + resid +
// LN2 (+ comb GEMM for next layer unless LAST). One block = 64 rows.
// BK=32 staging: LDS = 8 + 32 + 35 KB = 75KB -> 2 blocks/CU (4 waves/SIMD)
// for cross-block latency hiding (m114: occupancy overlap covers drains).
// y1 (LN1 out) lives in LDS qpS (FFN1 A-operand AND LN2 residual); after
// LN2 it is overwritten in place by bf16(y2+pos) for the comb GEMM.
// ---------------------------------------------------------------------------
template <int LAST>
__global__ __launch_bounds__(512, 4) void layer_kernel(
    const short* __restrict__ accb, const short* __restrict__ outTW,
    const float* __restrict__ outb, float* __restrict__ q,
    const float* __restrict__ ln1g, const float* __restrict__ ln1b,
    const short* __restrict__ f1T, const float* __restrict__ f1b,
    short* __restrict__ hid, const short* __restrict__ f2T,
    const float* __restrict__ f2b, const float* __restrict__ ln2g,
    const float* __restrict__ ln2b, const float* __restrict__ pos_row,
    const float* __restrict__ pos_col, const short* __restrict__ combTW,
    const float* __restrict__ comb_b, short* __restrict__ comb_bf) {
  constexpr int BK = 32, NW = 8, MT = 2, NT = 4;
  constexpr int AG = 4, BG = 16;
  constexpr int ASZ = 64 * BK, BSZ = 256 * BK;
  __shared__ short smem[2 * ASZ + 2 * BSZ + 64 * 280];
  short* const Asm = smem;
  short* const Bsm = smem + 2 * ASZ;
  short* const qpS = smem + 2 * ASZ + 2 * BSZ;
  float2* const lnpart = (float2*)Asm;   // [64][4], overlays As (dead then)
  const int tid = threadIdx.x;
  const int wave = tid >> 6, lane = tid & 63;
  const int wy = wave >> 2, wx = wave & 3;
  const long row0 = (long)blockIdx.y * 64;
  const int srow = lane >> 2;
  const int skof = ((lane & 3) ^ (srow & 3)) * 8;
  const int fr = lane & 15, fq = lane >> 4;
  const int ua = (fr * 4 + (fq ^ (fr & 3))) * 8;
  const int colb = wx * 64 + fr;
  const long rowb = row0 + wy * 32 + fq * 4;
  f32x4 acc[MT][NT];

  // main GEMM1-style k-loop: A (global, 64 rows), B (global, 256 rows)
  auto run_gemm = [&](const short* Ab, int lda, const short* Bb, int ldbt,
                      int ntiles) {
#pragma unroll
    for (int mt = 0; mt < MT; ++mt)
#pragma unroll
      for (int nt = 0; nt < NT; ++nt) acc[mt][nt] = f32x4{0.f, 0.f, 0.f, 0.f};
    auto stage = [&](int buf, int kt) {
      int k0 = kt * BK;
#pragma unroll
      for (int t = wave; t < AG + BG; t += NW) {
        if (t < AG) {
          gl_lds16(Ab + (long)(t * 16 + srow) * lda + k0 + skof,
                   &Asm[buf * ASZ + t * 512]);
        } else {
          int u = t - AG;
          gl_lds16(Bb + (long)(u * 16 + srow) * ldbt + k0 + skof,
                   &Bsm[buf * BSZ + u * 512]);
        }
      }
    };
    stage(0, 0);
    __syncthreads();
    int cur = 0;
    for (int t = 0; t < ntiles; ++t) {
      if (t + 1 < ntiles) stage(cur ^ 1, t + 1);
      bf16x8 af[MT], bfv[NT];
#pragma unroll
      for (int i = 0; i < MT; ++i)
        af[i] = *(const bf16x8*)&Asm[cur * ASZ + (wy * MT + i) * 512 + ua];
#pragma unroll
      for (int i = 0; i < NT; ++i)
        bfv[i] = *(const bf16x8*)&Bsm[cur * BSZ + (wx * 4 + i) * 512 + ua];
#pragma unroll
      for (int mt = 0; mt < MT; ++mt)
#pragma unroll
        for (int nt = 0; nt < NT; ++nt)
          acc[mt][nt] = __builtin_amdgcn_mfma_f32_16x16x32_bf16(
              af[mt], bfv[nt], acc[mt][nt], 0, 0, 0);
      __syncthreads();
      cur ^= 1;
    }
  };

  // LN over acc (+bias +resid): residf(row,col,rl); writer(rl,row,col,y)
  auto ln_epilogue = [&](const float* bias, auto residf, const float* g,
                         const float* b, auto writer) {
#pragma unroll
    for (int mt = 0; mt < MT; ++mt)
#pragma unroll
      for (int rr = 0; rr < 4; ++rr) {
        long row = rowb + mt * 16 + rr;
        int rl = wy * 32 + mt * 16 + fq * 4 + rr;
        float s = 0.f, s2 = 0.f;
#pragma unroll
        for (int nt = 0; nt < NT; ++nt) {
          int col = colb + nt * 16;
          float v = acc[mt][nt][rr] + bias[col] + residf(row, col, rl);
          acc[mt][nt][rr] = v;
          s += v; s2 += v * v;
        }
#pragma unroll
        for (int o = 8; o > 0; o >>= 1) {
          s += __shfl_xor(s, o);
          s2 += __shfl_xor(s2, o);
        }
        if (fr == 0) lnpart[rl * 4 + wx] = make_float2(s, s2);
      }
    __syncthreads();
#pragma unroll
    for (int mt = 0; mt < MT; ++mt)
#pragma unroll
      for (int rr = 0; rr < 4; ++rr) {
        int rl = wy * 32 + mt * 16 + fq * 4 + rr;
        long row = rowb + mt * 16 + rr;
        float s = 0.f, s2 = 0.f;
#pragma unroll
        for (int c = 0; c < 4; ++c) {
          s += lnpart[rl * 4 + c].x;
          s2 += lnpart[rl * 4 + c].y;
        }
        float m = s * (1.f / 256);
        float var = s2 * (1.f / 256) - m * m;
        float rs = rsqrtf(var + 1e-5f);
#pragma unroll
        for (int nt = 0; nt < NT; ++nt) {
          int col = colb + nt * 16;
          float y = (acc[mt][nt][rr] - m) * rs * g[col] + b[col];
          writer(rl, row, col, y);
        }
      }
  };

  // GEMM2-style: A = qpS (LDS, K=256), B = WT rows [hf*256, +256) x 256k
  auto run_gemm2 = [&](const short* WT, int nhalf, int ld2, bool dorelu,
                       const float* b2, short* out2) {
    auto stageW = [&](int buf, int t2) {
      int hf = t2 >> 3, k0 = (t2 & 7) * BK;
#pragma unroll
      for (int u = wave; u < BG; u += NW) {
        gl_lds16(WT + (long)(hf * 256 + u * 16 + srow) * 256 + k0 + skof,
                 &Bsm[buf * BSZ + u * 512]);
      }
    };
    const int NT2 = nhalf * 8;
    f32x4 acc2[4][NT];
#pragma unroll
    for (int mt = 0; mt < 4; ++mt)
#pragma unroll
      for (int t = 0; t < NT; ++t) acc2[mt][t] = f32x4{0.f, 0.f, 0.f, 0.f};
    stageW(0, 0);
    __syncthreads();
    int cur = 0;
    for (int t2 = 0; t2 < NT2; ++t2) {
      if (t2 + 1 < NT2) stageW(cur ^ 1, t2 + 1);
      int k0 = (t2 & 7) * BK;
#pragma unroll
      for (int mt = 0; mt < 4; ++mt) {
        bf16x8 av = *(const bf16x8*)&qpS[(mt * 16 + fr) * 280 + k0 + fq * 8];
#pragma unroll
        for (int t = 0; t < NT; ++t) {
          bf16x8 bv = *(const bf16x8*)&Bsm[cur * BSZ + (wx * 4 + t) * 512 + ua];
          acc2[mt][t] = __builtin_amdgcn_mfma_f32_16x16x32_bf16(
              av, bv, acc2[mt][t], 0, 0, 0);
        }
      }
      if ((t2 & 7) == 7) {
        int hf = t2 >> 3;
#pragma unroll
        for (int mt = 0; mt < 4; ++mt)
#pragma unroll
          for (int rr = 0; rr < 4; ++rr) {
            long row = row0 + mt * 16 + fq * 4 + rr;
#pragma unroll
            for (int nt = 0; nt < NT; ++nt) {
              int oc = hf * 256 + wx * 64 + nt * 16 + fr;
              float v = acc2[mt][nt][rr] + b2[oc];
              if (dorelu) v = fmaxf(v, 0.f);
              out2[row * ld2 + oc] = f2bf(v);
            }
          }
#pragma unroll
        for (int mt = 0; mt < 4; ++mt)
#pragma unroll
          for (int t = 0; t < NT; ++t) acc2[mt][t] = f32x4{0.f, 0.f, 0.f, 0.f};
      }
      __syncthreads();
      cur ^= 1;
    }
  };

  // ---- phase 1: out-proj + resid(q fp32) + LN1 -> qpS = bf16(y1)
  run_gemm(accb + row0 * 256, 256, outTW, 256, 8);
  ln_epilogue(
      outb, [&](long row, int col, int) { return q[row * 256 + col]; }, ln1g,
      ln1b,
      [&](int rl, long row, int col, float y) { qpS[rl * 280 + col] = f2bf(y); });
  // ---- phase 2: FFN1: hid = relu(y1 @ f1T^T + f1b)  (global scratch)
  run_gemm2(f1T, 2, 512, true, f1b, hid);
  // ---- phase 3: FFN2 + resid(y1 from qpS) + LN2 -> q; qpS = bf16(y2+pos)
  run_gemm(hid + row0 * 512, 512, f2T, 512, 16);
  ln_epilogue(
      f2b,
      [&](long row, int col, int rl) {
        return bf2f((unsigned short)qpS[rl * 280 + col]);
      },
      ln2g, ln2b,
      [&](int rl, long row, int col, float y) {
        q[row * 256 + col] = y;
        if (!LAST) {
          int wpos = (int)row & (kW - 1), hpos = (int)row >> 7;
          float pv = (col < 128) ? pos_col[wpos * 128 + col]
                                 : pos_row[hpos * 128 + (col - 128)];
          qpS[rl * 280 + col] = f2bf(y + pv);
        }
      });
  // ---- phase 4: comb GEMM for next layer
  if (!LAST) run_gemm2(combTW, 1, 256, false, comb_b, comb_bf);
}

// ---------------------------------------------------------------------------
// All weight conversions in one dispatch over a flat element space.
__global__ __launch_bounds__(256) void convert_all_kernel(
    const float* __restrict__ in_w, const float* __restrict__ val_w,
    const float* __restrict__ out_w, const float* __restrict__ ffn_w1,
    const float* __restrict__ ffn_w2, const float* __restrict__ off_w,
    const float* __restrict__ aw_w, const float* __restrict__ off_b,
    const float* __restrict__ aw_b,
    short* __restrict__ inT, short* __restrict__ valT, short* __restrict__ outT,
    short* __restrict__ ffn1T, short* __restrict__ ffn2T,
    short* __restrict__ combT, float* __restrict__ comb_bias) {
  long e = (long)blockIdx.x * 256 + threadIdx.x;
  if (e < 327680) {                       // inT: N=256, K=1280
    int idx = (int)e;
    int n = idx / 1280, k = idx - n * 1280;
    inT[idx] = f2bf(in_w[(long)k * 256 + n]);
    return;
  }
  e -= 327680;
  if (e < 393216) {                       // valT: N=256, K=256
    int z = (int)(e >> 16), idx = (int)e & 65535;
    int n = idx >> 8, k = idx & 255;
    valT[e] = f2bf(val_w[((long)z * 256 + k) * 256 + n]);
    return;
  }
  e -= 393216;
  if (e < 393216) {                       // outT: N=256, K=256
    int z = (int)(e >> 16), idx = (int)e & 65535;
    int n = idx >> 8, k = idx & 255;
    outT[e] = f2bf(out_w[((long)z * 256 + k) * 256 + n]);
    return;
  }
  e -= 393216;
  if (e < 786432) {                       // ffn1T: N=512, K=256
    int z = (int)(e / 131072);
    int idx = (int)(e - (long)z * 131072);
    int n = idx >> 8, k = idx & 255;
    ffn1T[e] = f2bf(ffn_w1[((long)z * 256 + k) * 512 + n]);
    return;
  }
  e -= 786432;
  if (e < 786432) {                       // ffn2T: N=256, K=512
    int z = (int)(e / 131072);
    int idx = (int)(e - (long)z * 131072);
    int n = idx >> 9, k = idx & 511;
    ffn2T[e] = f2bf(ffn_w2[((long)z * 512 + k) * 256 + n]);
    return;
  }
  e -= 786432;
  {                                       // combT: N=256(240), K=256
    int z = (int)(e >> 16), idx = (int)e & 65535;
    int n = idx >> 8, k = idx & 255;
    float v = 0.f;
    if (n < 160) v = off_w[((long)z * 256 + k) * 160 + n];
    else if (n < kCOMB) v = aw_w[((long)z * 256 + k) * 80 + (n - 160)];
    combT[e] = f2bf(v);
    if (k == 0)
      comb_bias[z * 256 + n] =
          (n < 160) ? off_b[z * 160 + n]
                    : (n < kCOMB ? aw_b[z * 80 + (n - 160)] : 0.f);
  }
}

// ---------------------------------------------------------------------------
// Fused per-level LN over channels of feat [L, C, nq] + transpose ->
// f bf16 [L, nq, C]. One read of feat.
__global__ __launch_bounds__(256) void ln_fused_kernel(
    const float* __restrict__ feat, const float* __restrict__ g,
    const float* __restrict__ b, short* __restrict__ f) {
  __shared__ float tile[256][33];
  __shared__ float2 part[8][32];
  __shared__ float mS[32], rsS[32];
  int l = blockIdx.y;
  int n0 = blockIdx.x * 32;
  int tx = threadIdx.x & 31;
  int ty = threadIdx.x >> 5;
  float s = 0.f, s2 = 0.f;
#pragma unroll 8
  for (int j = 0; j < 32; ++j) {
    int c = ty * 32 + j;
    float v = feat[((long)(l * kC + c)) * kNQ + n0 + tx];
    tile[c][tx] = v;
    s += v; s2 += v * v;
  }
  part[ty][tx] = make_float2(s, s2);
  __syncthreads();
  if (ty == 0) {
    float ss = 0.f, ss2 = 0.f;
#pragma unroll
    for (int j = 0; j < 8; ++j) {
      ss += part[j][tx].x; ss2 += part[j][tx].y;
    }
    float m = ss * (1.f / kC);
    float var = ss2 * (1.f / kC) - m * m;
    mS[tx] = m;
    rsS[tx] = rsqrtf(var + 1e-5f);
  }
  __syncthreads();
  int c = threadIdx.x;
  float gv = g[l * kC + c], bv = b[l * kC + c];
#pragma unroll 8
  for (int r = 0; r < 32; ++r) {
    float v = (tile[c][r] - mS[r]) * rsS[r] * gv + bv;
    f[((long)l * kNQ + n0 + r) * kC + c] = f2bf(v);
  }
}

// ---------------------------------------------------------------------------
// Deformable sampling: wave handles 2 queries (32 lanes each), all 4 heads.
__global__ __launch_bounds__(256) void sample_kernel(
    const unsigned short* __restrict__ comb, const short* __restrict__ val,
    short* __restrict__ accb) {
  __shared__ float2 ic[4][2][4][85];
  int wv = threadIdx.x >> 6;
  int lane = threadIdx.x & 63;
  int half = lane >> 5;
  int hl = lane & 31;
  int n = blockIdx.x * 8 + wv * 2 + half;
  int wq = n & (kW - 1);
  int hq = n >> 7;
  const unsigned short* cb = comb + (long)n * 256;
#pragma unroll
  for (int h = 0; h < 4; ++h) {
    float raw = (hl < 20) ? bf2f(cb[160 + h * 20 + hl]) : -1e30f;
    float mx = raw;
#pragma unroll
    for (int o = 16; o > 0; o >>= 1) mx = fmaxf(mx, __shfl_xor(mx, o));
    float ev = (hl < 20) ? __expf(raw - mx) : 0.f;
    float se = ev;
#pragma unroll
    for (int o = 16; o > 0; o >>= 1) se += __shfl_xor(se, o);
    if (hl < 20) {
      float awv = ev / se;
      int l = hl >> 2;
      float ox = bf2f(cb[h * 40 + hl * 2 + 0]);
      float oy = bf2f(cb[h * 40 + hl * 2 + 1]);
      float x = (float)wq + ox;
      float y = (float)hq + oy;
      float x0f = floorf(x), y0f = floorf(y);
      float fx = x - x0f, fy = y - y0f;
      int x0 = (int)x0f, y0 = (int)y0f;
#pragma unroll
      for (int c = 0; c < 4; ++c) {
        int dx = c & 1, dy = c >> 1;
        int ix = x0 + dx, iy = y0 + dy;
        float wgt = (dx ? fx : 1.f - fx) * (dy ? fy : 1.f - fy);
        bool valid = (ix >= 0 && ix < kW && iy >= 0 && iy < kH);
        int cix = min(max(ix, 0), kW - 1);
        int ciy = min(max(iy, 0), kH - 1);
        int sidx = ciy * kW + cix;
        int byteoff = (l * kNQ + sidx) * (kE * 2);
        float coef = valid ? awv * wgt : 0.f;
        ic[wv][half][h][hl * 4 + c] = make_float2(__int_as_float(byteoff), coef);
      }
    }
  }
  __syncthreads();
  int h2 = (lane >> 3) & 3;
  int ch8 = (lane & 7) * 8;
  const char* vb = (const char*)val + (h2 * 64 + ch8) * 2;
  const float2* icp = &ic[wv][half][h2][0];
  float a0 = 0.f, a1 = 0.f, a2 = 0.f, a3 = 0.f;
  float a4 = 0.f, a5 = 0.f, a6 = 0.f, a7 = 0.f;
#pragma unroll 4
  for (int j = 0; j < 80; ++j) {
    float2 oc = icp[j];
    int off = __float_as_int(oc.x);
    uint4 u = *(const uint4*)(vb + off);
    float cf = oc.y;
    a0 += cf * bflo(u.x); a1 += cf * bfhi(u.x);
    a2 += cf * bflo(u.y); a3 += cf * bfhi(u.y);
    a4 += cf * bflo(u.z); a5 += cf * bfhi(u.z);
    a6 += cf * bflo(u.w); a7 += cf * bfhi(u.w);
  }
  uint4 o;
  o.x = pack2(a0, a1); o.y = pack2(a2, a3);
  o.z = pack2(a4, a5); o.w = pack2(a6, a7);
  *(uint4*)(accb + (long)n * kE + h2 * 64 + ch8) = o;
}

// final transpose: out[e, n] = q[n, e]
__global__ __launch_bounds__(256) void transpose_kernel(
    const float* __restrict__ q, float* __restrict__ out) {
  __shared__ float t[32][33];
  int eb = blockIdx.x * 32, nb = blockIdx.y * 32;
  int tx = threadIdx.x & 31, ty = threadIdx.x >> 5;
#pragma unroll
  for (int j = 0; j < 4; ++j)
    t[ty + j * 8][tx] = q[(long)(nb + ty + j * 8) * kE + eb + tx];
  __syncthreads();
#pragma unroll
  for (int j = 0; j < 4; ++j)
    out[(long)(eb + ty + j * 8) * kNQ + nb + tx] = t[tx][ty + j * 8];
}

extern "C" void kernel_launch(void* const* d_in, const int* in_sizes, int n_in,
                              void* d_out, int out_size, void* d_ws,
                              size_t ws_size, hipStream_t stream) {
  const float* feat    = (const float*)d_in[0];
  const float* norm0_g = (const float*)d_in[1];
  const float* norm0_b = (const float*)d_in[2];
  const float* in_w    = (const float*)d_in[3];
  const float* in_b    = (const float*)d_in[4];
  const float* pos_row = (const float*)d_in[5];
  const float* pos_col = (const float*)d_in[6];
  const float* off_w   = (const float*)d_in[7];
  const float* off_b   = (const float*)d_in[8];
  const float* aw_w    = (const float*)d_in[9];
  const float* aw_b    = (const float*)d_in[10];
  const float* val_w   = (const float*)d_in[11];
  const float* val_b   = (const float*)d_in[12];
  const float* out_w   = (const float*)d_in[13];
  const float* out_b   = (const float*)d_in[14];
  const float* ln1_g   = (const float*)d_in[15];
  const float* ln1_b   = (const float*)d_in[16];
  const float* ln2_g   = (const float*)d_in[17];
  const float* ln2_b   = (const float*)d_in[18];
  const float* ffn_w1  = (const float*)d_in[19];
  const float* ffn_b1  = (const float*)d_in[20];
  const float* ffn_w2  = (const float*)d_in[21];
  const float* ffn_b2  = (const float*)d_in[22];

  char* p = (char*)d_ws;
  auto alloc = [&](size_t bytes) -> char* {
    char* r = p;
    p += (bytes + 255) & ~(size_t)255;
    return r;
  };
  const size_t valSlab = (size_t)kL * kNQ * kE;        // shorts per layer-val
  short* f_bf    = (short*)alloc((size_t)kL * kNQ * kC * 2);
  short* val_bf  = (short*)alloc(3 * valSlab * 2);     // 3 layer slabs
  float* q       = (float*)alloc((size_t)kNQ * kE * 4);
  short* accb    = (short*)alloc((size_t)kNQ * kE * 2);
  short* hid_bf  = (short*)alloc((size_t)kNQ * kFF * 2);
  short* comb_bf = (short*)alloc((size_t)kNQ * 256 * 2);
  float* comb_b  = (float*)alloc((size_t)kNL * 256 * 4);
  short* inT     = (short*)alloc((size_t)256 * 1280 * 2);
  short* valT    = (short*)alloc((size_t)kNL * 256 * 256 * 2);
  short* outT    = (short*)alloc((size_t)kNL * 256 * 256 * 2);
  short* ffn1T   = (short*)alloc((size_t)kNL * 512 * 256 * 2);
  short* ffn2T   = (short*)alloc((size_t)kNL * 256 * 512 * 2);
  short* combT   = (short*)alloc((size_t)kNL * 256 * 256 * 2);

  // all weight conversions in one dispatch
  convert_all_kernel<<<12032, 256, 0, stream>>>(
      in_w, val_w, out_w, ffn_w1, ffn_w2, off_w, aw_w, off_b, aw_b,
      inT, valT, outT, ffn1T, ffn2T, combT, comb_b);

  // fused feature LN (stats + apply + transpose) -> f bf16
  ln_fused_kernel<<<dim3(kNQ / 32, kL), 256, 0, stream>>>(feat, norm0_g,
                                                          norm0_b, f_bf);

  const long zouts = (long)kL * kNQ * 256 - 256;   // val z-stride correction
  // val for layers 0..2, batched: grid (3, 1280)
  gemm2_kernel<64, 0, 0><<<dim3(3, kL * kNQ / 64), 512, 0, stream>>>(
      f_bf, 0, kC, valT, 256, 256, 1, val_b,
      nullptr, val_bf, kE, 0, zouts, nullptr, nullptr,
      nullptr, nullptr, nullptr);

  // input proj (K=1280) + pos epilogue -> q fp32; fused layer-0 comb GEMM
  gemm2_kernel<64, 5, 0><<<dim3(1, kNQ / 64), 512, 0, stream>>>(
      f_bf, (long)kNQ * kC, kC, inT, 1280, 256, kL, in_b,
      q, nullptr, 256, 0, 0, pos_row, pos_col, combT, comb_b, comb_bf);

  for (int i = 0; i < kNL; ++i) {
    const short* outT_i  = outT + (long)i * 256 * 256;
    const short* f1T_i   = ffn1T + (long)i * 512 * 256;
    const short* f2T_i   = ffn2T + (long)i * 256 * 512;

    // fused softmax + sampling (reads slab i%3)
    sample_kernel<<<kNQ / 8, 256, 0, stream>>>(
        (const unsigned short*)comb_bf, val_bf + (long)(i % 3) * valSlab,
        accb);
    if (i == 2) {
      // val for layers 3..5 into the (now free) 3 slabs
      gemm2_kernel<64, 0, 0><<<dim3(3, kL * kNQ / 64), 512, 0, stream>>>(
          f_bf, 0, kC, valT + 3 * 256 * 256, 256, 256, 1, val_b + 3 * kE,
          nullptr, val_bf, kE, 0, zouts, nullptr, nullptr,
          nullptr, nullptr, nullptr);
    }
    // full layer: out-proj+LN1+FFN1+FFN2+LN2 (+comb for i+1)
    if (i + 1 < kNL) {
      layer_kernel<0><<<dim3(1, kNQ / 64), 512, 0, stream>>>(
          accb, outT_i, out_b + (long)i * kE, q,
          ln1_g + (long)i * kE, ln1_b + (long)i * kE,
          f1T_i, ffn_b1 + (long)i * kFF, hid_bf,
          f2T_i, ffn_b2 + (long)i * kE,
          ln2_g + (long)i * kE, ln2_b + (long)i * kE,
          pos_row, pos_col,
          combT + (long)(i + 1) * 256 * 256, comb_b + (i + 1) * 256, comb_bf);
    } else {
      layer_kernel<1><<<dim3(1, kNQ / 64), 512, 0, stream>>>(
          accb, outT_i, out_b + (long)i * kE, q,
          ln1_g + (long)i * kE, ln1_b + (long)i * kE,
          f1T_i, ffn_b1 + (long)i * kFF, hid_bf,
          f2T_i, ffn_b2 + (long)i * kE,
          ln2_g + (long)i * kE, ln2_b + (long)i * kE,
          pos_row, pos_col, nullptr, nullptr, nullptr);
    }
  }

  transpose_kernel<<<dim3(kE / 32, kNQ / 32), 256, 0, stream>>>(q,
                                                                (float*)d_out);
}

// Round 9
// 822.559 us; speedup vs baseline: 1.3379x; 1.3379x over previous
//
#include <hip/hip_runtime.h>
#include <hip/hip_bf16.h>
#include <stdint.h>

static constexpr int kL  = 5;
static constexpr int kNH = 4;
static constexpr int kP  = 4;
static constexpr int kE  = 256;
static constexpr int kC  = 256;
static constexpr int kH  = 128;
static constexpr int kW  = 128;
static constexpr int kNQ = kH * kW;          // 16384
static constexpr int kNL = 6;
static constexpr int kFF = 2 * kE;           // 512
static constexpr int kCOMB = 240;            // 160 off + 80 aw (stored ld 256)

typedef short bf16x8 __attribute__((ext_vector_type(8)));
typedef float f32x4 __attribute__((ext_vector_type(4)));

__device__ __forceinline__ short f2bf(float x) {
  union { float f; uint32_t u; } v; v.f = x;
  uint32_t r = v.u + 0x7fffu + ((v.u >> 16) & 1u);
  return (short)(r >> 16);
}
__device__ __forceinline__ uint32_t pack2(float a, float b) {
  return (uint32_t)(unsigned short)f2bf(a) | ((uint32_t)(unsigned short)f2bf(b) << 16);
}
__device__ __forceinline__ float bflo(uint32_t u) { return __uint_as_float(u << 16); }
__device__ __forceinline__ float bfhi(uint32_t u) { return __uint_as_float(u & 0xffff0000u); }
__device__ __forceinline__ float bf2f(unsigned short u) {
  return __uint_as_float((uint32_t)u << 16);
}

__device__ __forceinline__ void gl_lds16(const void* g, void* l) {
  __builtin_amdgcn_global_load_lds(
      (const __attribute__((address_space(1))) void*)g,
      (__attribute__((address_space(3))) void*)l, 16, 0, 0);
}

// ---------------------------------------------------------------------------
// LDS-staged bf16 MFMA GEMM, 512 threads (8 waves, 2Mx4N), BM=64, BN=256,
// BK=64, 2-phase double-buffered pipeline (STAGE(t+1) before compute(t),
// one barrier per tile). Staging unit = 1KB group (16 rows x 32 k),
// pre-swizzled source (skof) + swizzled fragment read (ua).
// MODE 0: bias (+relu) -> Cf and/or Cb (Cb z-strided by zouts*blockIdx.x)
// MODE 5: v=acc+bias -> Cf fp32 (q); qpS = bf16(v+pos); fused comb GEMM2
//         (wy-split: each wave owns 32 rows -> no duplicate MFMA work)
// ---------------------------------------------------------------------------
template <int BM, int MODE, int RB>
__global__ __launch_bounds__(512, MODE == 0 ? 4 : 2) void gemm2_kernel(
    const short* __restrict__ A, long sAb, int lda,
    const short* __restrict__ BT, int ldbt, int Kb, int nbatch,
    const float* __restrict__ bias,
    float* Cf, short* __restrict__ Cb, int ldc, int relu, long zouts,
    const float* __restrict__ pos_row, const float* __restrict__ pos_col,
    const short* __restrict__ w2BT, const float* __restrict__ w2B,
    short* __restrict__ out2) {
  static_assert(BM == 64, "layout assumes BM=64");
  constexpr bool FUSED = (MODE == 5);
  constexpr int BK = 64;
  constexpr int KG = 2;
  constexpr int NW = 8;
  constexpr int MT = 2;
  constexpr int NT = 4;
  constexpr int AG = (BM / 16) * KG;   // 8
  constexpr int BG = 16 * KG;          // 32
  constexpr int ASZ = BM * BK;
  constexpr int BSZ = 256 * BK;
  __shared__ short smem[2 * ASZ + 2 * BSZ + (FUSED ? 64 * 280 : 0)];
  short* const Asm = smem;
  short* const Bsm = smem + 2 * ASZ;
  short* const qpS = smem + 2 * ASZ + 2 * BSZ;          // FUSED only
  const int tid = threadIdx.x;
  const int wave = tid >> 6, lane = tid & 63;
  const int wy = wave >> 2, wx = wave & 3;
  const long row0 = (long)blockIdx.y * BM;
  const int col0 = blockIdx.x * 256;
  const int srow = lane >> 2;
  const int skof = ((lane & 3) ^ (srow & 3)) * 8;
  const int fr = lane & 15, fq = lane >> 4;
  const int ua = (fr * 4 + (fq ^ (fr & 3))) * 8;
  f32x4 acc[MT][NT] = {};
  const int KT = Kb >> 6;
  const int NTILES = nbatch * KT;

  auto stage_tile = [&](int buf, int bb, int kt) {
    const short* Ab = A + (long)bb * sAb + row0 * lda;
    const short* Bb = BT + (long)col0 * ldbt + (long)bb * Kb;
    int k0 = kt * BK;
#pragma unroll
    for (int t = wave; t < AG + BG; t += NW) {
      if (t < AG) {
        int rg = t >> 1, kg = t & 1;
        gl_lds16(Ab + (long)(rg * 16 + srow) * lda + k0 + kg * 32 + skof,
                 &Asm[buf * ASZ + t * 512]);
      } else {
        int u = t - AG;
        int rg = u >> 1, kg = u & 1;
        gl_lds16(Bb + (long)(rg * 16 + srow) * ldbt + k0 + kg * 32 + skof,
                 &Bsm[buf * BSZ + u * 512]);
      }
    }
  };

  int cur = 0;
  stage_tile(0, 0, 0);
  __syncthreads();
  int sb = 0, sk = 0;
  for (int idx = 0; idx < NTILES; ++idx) {
    if (idx + 1 < NTILES) {
      if (++sk == KT) { sk = 0; ++sb; }
      stage_tile(cur ^ 1, sb, sk);
    }
#pragma unroll
    for (int kk = 0; kk < KG; ++kk) {
      bf16x8 af[MT], bfv[NT];
#pragma unroll
      for (int t = 0; t < MT; ++t)
        af[t] = *(const bf16x8*)&Asm[cur * ASZ + ((wy * MT + t) * KG + kk) * 512 + ua];
#pragma unroll
      for (int t = 0; t < NT; ++t)
        bfv[t] = *(const bf16x8*)&Bsm[cur * BSZ + ((wx * 4 + t) * KG + kk) * 512 + ua];
#pragma unroll
      for (int mt = 0; mt < MT; ++mt)
#pragma unroll
        for (int nt = 0; nt < NT; ++nt)
          acc[mt][nt] = __builtin_amdgcn_mfma_f32_16x16x32_bf16(
              af[mt], bfv[nt], acc[mt][nt], 0, 0, 0);
    }
    __syncthreads();
    cur ^= 1;
  }

  const int colb = col0 + wx * 64 + fr;            // + nt*16
  const long rowb = row0 + wy * 32 + fq * 4;       // + mt*16 + rr

  if (MODE == 0) {
    const long zoff = (long)blockIdx.x * zouts;
#pragma unroll
    for (int mt = 0; mt < MT; ++mt)
#pragma unroll
      for (int rr = 0; rr < 4; ++rr) {
        long row = rowb + mt * 16 + rr;
#pragma unroll
        for (int nt = 0; nt < NT; ++nt) {
          int col = colb + nt * 16;
          float v = acc[mt][nt][rr] + bias[col];
          if (relu) v = fmaxf(v, 0.f);
          if (Cf) Cf[row * ldc + col] = v;
          if (Cb) Cb[zoff + row * ldc + col] = f2bf(v);
        }
      }
  } else if (MODE == 5) {
#pragma unroll
    for (int mt = 0; mt < MT; ++mt)
#pragma unroll
      for (int rr = 0; rr < 4; ++rr) {
        long row = rowb + mt * 16 + rr;
        int rl = wy * 32 + mt * 16 + fq * 4 + rr;
        int wpos = (int)row & (kW - 1), hpos = (int)row >> 7;
#pragma unroll
        for (int nt = 0; nt < NT; ++nt) {
          int col = colb + nt * 16;
          float v = acc[mt][nt][rr] + bias[col];
          Cf[row * 256 + col] = v;
          float pv = (col < 128) ? pos_col[wpos * 128 + col]
                                 : pos_row[hpos * 128 + (col - 128)];
          qpS[rl * 280 + col] = f2bf(v + pv);
        }
      }
  }
  if constexpr (FUSED) {
    // fused comb GEMM2 (wy-split, MT=2): out2 = qpS @ w2BT^T + w2B
    auto stageW = [&](int buf, int t2) {
      int k0 = t2 * BK;
#pragma unroll
      for (int u = wave; u < BG; u += NW) {
        int rg = u >> 1, kg = u & 1;
        gl_lds16(w2BT + (long)(rg * 16 + srow) * 256 + k0 + kg * 32 + skof,
                 &Bsm[buf * BSZ + u * 512]);
      }
    };
    f32x4 acc2[MT][NT] = {};
    stageW(cur, 0);
    __syncthreads();
    for (int t2 = 0; t2 < 4; ++t2) {
      if (t2 + 1 < 4) stageW(cur ^ 1, t2 + 1);
      int k0 = t2 * BK;
#pragma unroll
      for (int kk = 0; kk < KG; ++kk) {
        bf16x8 av[MT], bv[NT];
#pragma unroll
        for (int mt = 0; mt < MT; ++mt)
          av[mt] = *(const bf16x8*)&qpS[(wy * 32 + mt * 16 + fr) * 280 + k0 +
                                        kk * 32 + fq * 8];
#pragma unroll
        for (int t = 0; t < NT; ++t)
          bv[t] = *(const bf16x8*)&Bsm[cur * BSZ + ((wx * 4 + t) * KG + kk) *
                                           512 + ua];
#pragma unroll
        for (int mt = 0; mt < MT; ++mt)
#pragma unroll
          for (int t = 0; t < NT; ++t)
            acc2[mt][t] = __builtin_amdgcn_mfma_f32_16x16x32_bf16(
                av[mt], bv[t], acc2[mt][t], 0, 0, 0);
      }
      __syncthreads();
      cur ^= 1;
    }
#pragma unroll
    for (int mt = 0; mt < MT; ++mt)
#pragma unroll
      for (int rr = 0; rr < 4; ++rr) {
        long row = row0 + wy * 32 + mt * 16 + fq * 4 + rr;
#pragma unroll
        for (int nt = 0; nt < NT; ++nt) {
          int oc = wx * 64 + nt * 16 + fr;
          out2[row * 256 + oc] = f2bf(acc2[mt][nt][rr] + w2B[oc]);
        }
      }
  }
}

// ---------------------------------------------------------------------------
// Full-layer fused kernel: out-proj + resid + LN1 + FFN (halved, LDS-only)
// + resid + LN2 (+ comb GEMM for next layer unless LAST). One block = 64
// rows. FFN never materializes hid in global: for hf in {0,1}:
//   hS = relu(y1 @ W1[:,hf*256:+256] + b1h)   (35KB LDS, aliases dead Asm)
//   acc += hS @ W2[hf*256:+256, :]            (accumulate both halves)
// All LDS-A GEMMs are wy-split (each wave owns 32 rows -> no duplicate
// MFMA). y1 lives in qpS (FFN A-operand AND LN2 residual); after LN2 it is
// overwritten in place by bf16(y2+pos) for the comb GEMM.
// LDS: union(Asm 16K, hS 35K, lnpart 2K) + Bsm 64K + qpS 35K = 134.2KB.
// ---------------------------------------------------------------------------
template <int LAST>
__global__ __launch_bounds__(512, 2) void layer_kernel(
    const short* __restrict__ accb, const short* __restrict__ outTW,
    const float* __restrict__ outb, float* __restrict__ q,
    const float* __restrict__ ln1g, const float* __restrict__ ln1b,
    const short* __restrict__ f1T, const float* __restrict__ f1b,
    const short* __restrict__ f2T, const float* __restrict__ f2b,
    const float* __restrict__ ln2g, const float* __restrict__ ln2b,
    const float* __restrict__ pos_row, const float* __restrict__ pos_col,
    const short* __restrict__ combTW, const float* __restrict__ comb_b,
    short* __restrict__ comb_bf) {
  constexpr int BK = 64, KG = 2, NW = 8, MT = 2, NT = 4;
  constexpr int AG = 8, BG = 32;
  constexpr int ASZ = 64 * BK, BSZ = 256 * BK;
  __shared__ short smem[64 * 280 + 2 * BSZ + 64 * 280];
  short* const Asm = smem;                 // phase-1 staging (16KB of 35KB)
  short* const hS  = smem;                 // FFN half buffer, aliases Asm
  short* const Bsm = smem + 64 * 280;
  short* const qpS = smem + 64 * 280 + 2 * BSZ;
  float2* const lnpart = (float2*)smem;    // [64][4], aliases Asm/hS (dead)
  const int tid = threadIdx.x;
  const int wave = tid >> 6, lane = tid & 63;
  const int wy = wave >> 2, wx = wave & 3;
  const long row0 = (long)blockIdx.y * 64;
  const int srow = lane >> 2;
  const int skof = ((lane & 3) ^ (srow & 3)) * 8;
  const int fr = lane & 15, fq = lane >> 4;
  const int ua = (fr * 4 + (fq ^ (fr & 3))) * 8;
  const int colb = wx * 64 + fr;
  const long rowb = row0 + wy * 32 + fq * 4;
  f32x4 acc[MT][NT];

  // phase-1 GEMM: A (global, 64 rows) staged, B (global, 256 rows) staged
  auto run_gemm = [&](const short* Ab, int lda, const short* Bb, int ldbt,
                      int ntiles) {
#pragma unroll
    for (int mt = 0; mt < MT; ++mt)
#pragma unroll
      for (int nt = 0; nt < NT; ++nt) acc[mt][nt] = f32x4{0.f, 0.f, 0.f, 0.f};
    auto stage = [&](int buf, int kt) {
      int k0 = kt * BK;
#pragma unroll
      for (int t = wave; t < AG + BG; t += NW) {
        if (t < AG) {
          int rg = t >> 1, kg = t & 1;
          gl_lds16(Ab + (long)(rg * 16 + srow) * lda + k0 + kg * 32 + skof,
                   &Asm[buf * ASZ + t * 512]);
        } else {
          int u = t - AG, rg = u >> 1, kg = u & 1;
          gl_lds16(Bb + (long)(rg * 16 + srow) * ldbt + k0 + kg * 32 + skof,
                   &Bsm[buf * BSZ + u * 512]);
        }
      }
    };
    stage(0, 0);
    __syncthreads();
    int cur = 0;
    for (int t = 0; t < ntiles; ++t) {
      if (t + 1 < ntiles) stage(cur ^ 1, t + 1);
#pragma unroll
      for (int kk = 0; kk < KG; ++kk) {
        bf16x8 af[MT], bfv[NT];
#pragma unroll
        for (int i = 0; i < MT; ++i)
          af[i] = *(const bf16x8*)&Asm[cur * ASZ +
                                       ((wy * MT + i) * KG + kk) * 512 + ua];
#pragma unroll
        for (int i = 0; i < NT; ++i)
          bfv[i] = *(const bf16x8*)&Bsm[cur * BSZ +
                                        ((wx * 4 + i) * KG + kk) * 512 + ua];
#pragma unroll
        for (int mt = 0; mt < MT; ++mt)
#pragma unroll
          for (int nt = 0; nt < NT; ++nt)
            acc[mt][nt] = __builtin_amdgcn_mfma_f32_16x16x32_bf16(
                af[mt], bfv[nt], acc[mt][nt], 0, 0, 0);
      }
      __syncthreads();
      cur ^= 1;
    }
  };

  // LDS-A GEMM (wy-split): dst += As_lds(rows wy*32.., pitch 280, k 0..255)
  //                              @ B(WT 256 rows x ldw, k = kofs..+256)
  auto ldsA_gemm = [&](const short* As_lds, const short* WT, int ldw,
                       int kofs, f32x4(&dst)[MT][NT]) {
    auto stg = [&](int buf, int t2) {
      int k0 = kofs + t2 * BK;
#pragma unroll
      for (int u = wave; u < BG; u += NW) {
        int rg = u >> 1, kg = u & 1;
        gl_lds16(WT + (long)(rg * 16 + srow) * ldw + k0 + kg * 32 + skof,
                 &Bsm[buf * BSZ + u * 512]);
      }
    };
    stg(0, 0);
    __syncthreads();
    int cur = 0;
    for (int t2 = 0; t2 < 4; ++t2) {
      if (t2 + 1 < 4) stg(cur ^ 1, t2 + 1);
      int k0 = t2 * BK;
#pragma unroll
      for (int kk = 0; kk < KG; ++kk) {
        bf16x8 av[MT], bv[NT];
#pragma unroll
        for (int mt = 0; mt < MT; ++mt)
          av[mt] = *(const bf16x8*)&As_lds[(wy * 32 + mt * 16 + fr) * 280 +
                                           k0 + kk * 32 + fq * 8];
#pragma unroll
        for (int t = 0; t < NT; ++t)
          bv[t] = *(const bf16x8*)&Bsm[cur * BSZ +
                                       ((wx * 4 + t) * KG + kk) * 512 + ua];
#pragma unroll
        for (int mt = 0; mt < MT; ++mt)
#pragma unroll
          for (int t = 0; t < NT; ++t)
            dst[mt][t] = __builtin_amdgcn_mfma_f32_16x16x32_bf16(
                av[mt], bv[t], dst[mt][t], 0, 0, 0);
      }
      __syncthreads();
      cur ^= 1;
    }
  };

  // LN over acc (+bias +resid): residf(row,col,rl); writer(rl,row,col,y)
  auto ln_epilogue = [&](const float* bias, auto residf, const float* g,
                         const float* b, auto writer) {
#pragma unroll
    for (int mt = 0; mt < MT; ++mt)
#pragma unroll
      for (int rr = 0; rr < 4; ++rr) {
        long row = rowb + mt * 16 + rr;
        int rl = wy * 32 + mt * 16 + fq * 4 + rr;
        float s = 0.f, s2 = 0.f;
#pragma unroll
        for (int nt = 0; nt < NT; ++nt) {
          int col = colb + nt * 16;
          float v = acc[mt][nt][rr] + bias[col] + residf(row, col, rl);
          acc[mt][nt][rr] = v;
          s += v; s2 += v * v;
        }
#pragma unroll
        for (int o = 8; o > 0; o >>= 1) {
          s += __shfl_xor(s, o);
          s2 += __shfl_xor(s2, o);
        }
        if (fr == 0) lnpart[rl * 4 + wx] = make_float2(s, s2);
      }
    __syncthreads();
#pragma unroll
    for (int mt = 0; mt < MT; ++mt)
#pragma unroll
      for (int rr = 0; rr < 4; ++rr) {
        int rl = wy * 32 + mt * 16 + fq * 4 + rr;
        long row = rowb + mt * 16 + rr;
        float s = 0.f, s2 = 0.f;
#pragma unroll
        for (int c = 0; c < 4; ++c) {
          s += lnpart[rl * 4 + c].x;
          s2 += lnpart[rl * 4 + c].y;
        }
        float m = s * (1.f / 256);
        float var = s2 * (1.f / 256) - m * m;
        float rs = rsqrtf(var + 1e-5f);
#pragma unroll
        for (int nt = 0; nt < NT; ++nt) {
          int col = colb + nt * 16;
          float y = (acc[mt][nt][rr] - m) * rs * g[col] + b[col];
          writer(rl, row, col, y);
        }
      }
  };

  // ---- phase 1: out-proj + resid(q fp32) + LN1 -> qpS = bf16(y1)
  run_gemm(accb + row0 * 256, 256, outTW, 256, 4);
  ln_epilogue(
      outb, [&](long row, int col, int) { return q[row * 256 + col]; }, ln1g,
      ln1b,
      [&](int rl, long row, int col, float y) { qpS[rl * 280 + col] = f2bf(y); });
  __syncthreads();   // qpS (y1) visible to all waves before FFN reads

  // ---- phase 2: FFN via halves, no global hid
#pragma unroll
  for (int mt = 0; mt < MT; ++mt)
#pragma unroll
    for (int nt = 0; nt < NT; ++nt) acc[mt][nt] = f32x4{0.f, 0.f, 0.f, 0.f};
  for (int hf = 0; hf < 2; ++hf) {
    // FFN1 half -> hS (relu + bias)
    f32x4 a1[MT][NT] = {};
    ldsA_gemm(qpS, f1T + (long)(hf * 256) * 256, 256, 0, a1);
#pragma unroll
    for (int mt = 0; mt < MT; ++mt)
#pragma unroll
      for (int rr = 0; rr < 4; ++rr) {
        int rl = wy * 32 + mt * 16 + fq * 4 + rr;
#pragma unroll
        for (int nt = 0; nt < NT; ++nt) {
          int col = colb + nt * 16;
          float v = a1[mt][nt][rr] + f1b[hf * 256 + col];
          hS[rl * 280 + col] = f2bf(fmaxf(v, 0.f));
        }
      }
    __syncthreads();   // hS complete
    // FFN2 half: acc += hS @ W2[hf*256:+256, :]
    ldsA_gemm(hS, f2T, 512, hf * 256, acc);
  }
  // ---- LN2: resid = y1 (qpS); -> q fp32; qpS = bf16(y2+pos)
  ln_epilogue(
      f2b,
      [&](long row, int col, int rl) {
        return bf2f((unsigned short)qpS[rl * 280 + col]);
      },
      ln2g, ln2b,
      [&](int rl, long row, int col, float y) {
        q[row * 256 + col] = y;
        if (!LAST) {
          int wpos = (int)row & (kW - 1), hpos = (int)row >> 7;
          float pv = (col < 128) ? pos_col[wpos * 128 + col]
                                 : pos_row[hpos * 128 + (col - 128)];
          qpS[rl * 280 + col] = f2bf(y + pv);
        }
      });
  // ---- phase 3: comb GEMM for next layer
  if (!LAST) {
    __syncthreads();   // qpS (y2+pos) visible
    f32x4 a2[MT][NT] = {};
    ldsA_gemm(qpS, combTW, 256, 0, a2);
#pragma unroll
    for (int mt = 0; mt < MT; ++mt)
#pragma unroll
      for (int rr = 0; rr < 4; ++rr) {
        long row = row0 + wy * 32 + mt * 16 + fq * 4 + rr;
#pragma unroll
        for (int nt = 0; nt < NT; ++nt) {
          int oc = wx * 64 + nt * 16 + fr;
          comb_bf[row * 256 + oc] = f2bf(a2[mt][nt][rr] + comb_b[oc]);
        }
      }
  }
}

// ---------------------------------------------------------------------------
// All weight conversions in one dispatch over a flat element space.
__global__ __launch_bounds__(256) void convert_all_kernel(
    const float* __restrict__ in_w, const float* __restrict__ val_w,
    const float* __restrict__ out_w, const float* __restrict__ ffn_w1,
    const float* __restrict__ ffn_w2, const float* __restrict__ off_w,
    const float* __restrict__ aw_w, const float* __restrict__ off_b,
    const float* __restrict__ aw_b,
    short* __restrict__ inT, short* __restrict__ valT, short* __restrict__ outT,
    short* __restrict__ ffn1T, short* __restrict__ ffn2T,
    short* __restrict__ combT, float* __restrict__ comb_bias) {
  long e = (long)blockIdx.x * 256 + threadIdx.x;
  if (e < 327680) {                       // inT: N=256, K=1280
    int idx = (int)e;
    int n = idx / 1280, k = idx - n * 1280;
    inT[idx] = f2bf(in_w[(long)k * 256 + n]);
    return;
  }
  e -= 327680;
  if (e < 393216) {                       // valT: N=256, K=256
    int z = (int)(e >> 16), idx = (int)e & 65535;
    int n = idx >> 8, k = idx & 255;
    valT[e] = f2bf(val_w[((long)z * 256 + k) * 256 + n]);
    return;
  }
  e -= 393216;
  if (e < 393216) {                       // outT: N=256, K=256
    int z = (int)(e >> 16), idx = (int)e & 65535;
    int n = idx >> 8, k = idx & 255;
    outT[e] = f2bf(out_w[((long)z * 256 + k) * 256 + n]);
    return;
  }
  e -= 393216;
  if (e < 786432) {                       // ffn1T: N=512, K=256
    int z = (int)(e / 131072);
    int idx = (int)(e - (long)z * 131072);
    int n = idx >> 8, k = idx & 255;
    ffn1T[e] = f2bf(ffn_w1[((long)z * 256 + k) * 512 + n]);
    return;
  }
  e -= 786432;
  if (e < 786432) {                       // ffn2T: N=256, K=512
    int z = (int)(e / 131072);
    int idx = (int)(e - (long)z * 131072);
    int n = idx >> 9, k = idx & 511;
    ffn2T[e] = f2bf(ffn_w2[((long)z * 512 + k) * 256 + n]);
    return;
  }
  e -= 786432;
  {                                       // combT: N=256(240), K=256
    int z = (int)(e >> 16), idx = (int)e & 65535;
    int n = idx >> 8, k = idx & 255;
    float v = 0.f;
    if (n < 160) v = off_w[((long)z * 256 + k) * 160 + n];
    else if (n < kCOMB) v = aw_w[((long)z * 256 + k) * 80 + (n - 160)];
    combT[e] = f2bf(v);
    if (k == 0)
      comb_bias[z * 256 + n] =
          (n < 160) ? off_b[z * 160 + n]
                    : (n < kCOMB ? aw_b[z * 80 + (n - 160)] : 0.f);
  }
}

// ---------------------------------------------------------------------------
// Fused per-level LN over channels of feat [L, C, nq] + transpose ->
// f bf16 [L, nq, C]. One read of feat.
__global__ __launch_bounds__(256) void ln_fused_kernel(
    const float* __restrict__ feat, const float* __restrict__ g,
    const float* __restrict__ b, short* __restrict__ f) {
  __shared__ float tile[256][33];
  __shared__ float2 part[8][32];
  __shared__ float mS[32], rsS[32];
  int l = blockIdx.y;
  int n0 = blockIdx.x * 32;
  int tx = threadIdx.x & 31;
  int ty = threadIdx.x >> 5;
  float s = 0.f, s2 = 0.f;
#pragma unroll 8
  for (int j = 0; j < 32; ++j) {
    int c = ty * 32 + j;
    float v = feat[((long)(l * kC + c)) * kNQ + n0 + tx];
    tile[c][tx] = v;
    s += v; s2 += v * v;
  }
  part[ty][tx] = make_float2(s, s2);
  __syncthreads();
  if (ty == 0) {
    float ss = 0.f, ss2 = 0.f;
#pragma unroll
    for (int j = 0; j < 8; ++j) {
      ss += part[j][tx].x; ss2 += part[j][tx].y;
    }
    float m = ss * (1.f / kC);
    float var = ss2 * (1.f / kC) - m * m;
    mS[tx] = m;
    rsS[tx] = rsqrtf(var + 1e-5f);
  }
  __syncthreads();
  int c = threadIdx.x;
  float gv = g[l * kC + c], bv = b[l * kC + c];
#pragma unroll 8
  for (int r = 0; r < 32; ++r) {
    float v = (tile[c][r] - mS[r]) * rsS[r] * gv + bv;
    f[((long)l * kNQ + n0 + r) * kC + c] = f2bf(v);
  }
}

// ---------------------------------------------------------------------------
// Deformable sampling: wave handles 2 queries (32 lanes each), all 4 heads.
__global__ __launch_bounds__(256) void sample_kernel(
    const unsigned short* __restrict__ comb, const short* __restrict__ val,
    short* __restrict__ accb) {
  __shared__ float2 ic[4][2][4][85];
  int wv = threadIdx.x >> 6;
  int lane = threadIdx.x & 63;
  int half = lane >> 5;
  int hl = lane & 31;
  int n = blockIdx.x * 8 + wv * 2 + half;
  int wq = n & (kW - 1);
  int hq = n >> 7;
  const unsigned short* cb = comb + (long)n * 256;
#pragma unroll
  for (int h = 0; h < 4; ++h) {
    float raw = (hl < 20) ? bf2f(cb[160 + h * 20 + hl]) : -1e30f;
    float mx = raw;
#pragma unroll
    for (int o = 16; o > 0; o >>= 1) mx = fmaxf(mx, __shfl_xor(mx, o));
    float ev = (hl < 20) ? __expf(raw - mx) : 0.f;
    float se = ev;
#pragma unroll
    for (int o = 16; o > 0; o >>= 1) se += __shfl_xor(se, o);
    if (hl < 20) {
      float awv = ev / se;
      int l = hl >> 2;
      float ox = bf2f(cb[h * 40 + hl * 2 + 0]);
      float oy = bf2f(cb[h * 40 + hl * 2 + 1]);
      float x = (float)wq + ox;
      float y = (float)hq + oy;
      float x0f = floorf(x), y0f = floorf(y);
      float fx = x - x0f, fy = y - y0f;
      int x0 = (int)x0f, y0 = (int)y0f;
#pragma unroll
      for (int c = 0; c < 4; ++c) {
        int dx = c & 1, dy = c >> 1;
        int ix = x0 + dx, iy = y0 + dy;
        float wgt = (dx ? fx : 1.f - fx) * (dy ? fy : 1.f - fy);
        bool valid = (ix >= 0 && ix < kW && iy >= 0 && iy < kH);
        int cix = min(max(ix, 0), kW - 1);
        int ciy = min(max(iy, 0), kH - 1);
        int sidx = ciy * kW + cix;
        int byteoff = (l * kNQ + sidx) * (kE * 2);
        float coef = valid ? awv * wgt : 0.f;
        ic[wv][half][h][hl * 4 + c] = make_float2(__int_as_float(byteoff), coef);
      }
    }
  }
  __syncthreads();
  int h2 = (lane >> 3) & 3;
  int ch8 = (lane & 7) * 8;
  const char* vb = (const char*)val + (h2 * 64 + ch8) * 2;
  const float2* icp = &ic[wv][half][h2][0];
  float a0 = 0.f, a1 = 0.f, a2 = 0.f, a3 = 0.f;
  float a4 = 0.f, a5 = 0.f, a6 = 0.f, a7 = 0.f;
#pragma unroll 4
  for (int j = 0; j < 80; ++j) {
    float2 oc = icp[j];
    int off = __float_as_int(oc.x);
    uint4 u = *(const uint4*)(vb + off);
    float cf = oc.y;
    a0 += cf * bflo(u.x); a1 += cf * bfhi(u.x);
    a2 += cf * bflo(u.y); a3 += cf * bfhi(u.y);
    a4 += cf * bflo(u.z); a5 += cf * bfhi(u.z);
    a6 += cf * bflo(u.w); a7 += cf * bfhi(u.w);
  }
  uint4 o;
  o.x = pack2(a0, a1); o.y = pack2(a2, a3);
  o.z = pack2(a4, a5); o.w = pack2(a6, a7);
  *(uint4*)(accb + (long)n * kE + h2 * 64 + ch8) = o;
}

// final transpose: out[e, n] = q[n, e]
__global__ __launch_bounds__(256) void transpose_kernel(
    const float* __restrict__ q, float* __restrict__ out) {
  __shared__ float t[32][33];
  int eb = blockIdx.x * 32, nb = blockIdx.y * 32;
  int tx = threadIdx.x & 31, ty = threadIdx.x >> 5;
#pragma unroll
  for (int j = 0; j < 4; ++j)
    t[ty + j * 8][tx] = q[(long)(nb + ty + j * 8) * kE + eb + tx];
  __syncthreads();
#pragma unroll
  for (int j = 0; j < 4; ++j)
    out[(long)(eb + ty + j * 8) * kNQ + nb + tx] = t[tx][ty + j * 8];
}

extern "C" void kernel_launch(void* const* d_in, const int* in_sizes, int n_in,
                              void* d_out, int out_size, void* d_ws,
                              size_t ws_size, hipStream_t stream) {
  const float* feat    = (const float*)d_in[0];
  const float* norm0_g = (const float*)d_in[1];
  const float* norm0_b = (const float*)d_in[2];
  const float* in_w    = (const float*)d_in[3];
  const float* in_b    = (const float*)d_in[4];
  const float* pos_row = (const float*)d_in[5];
  const float* pos_col = (const float*)d_in[6];
  const float* off_w   = (const float*)d_in[7];
  const float* off_b   = (const float*)d_in[8];
  const float* aw_w    = (const float*)d_in[9];
  const float* aw_b    = (const float*)d_in[10];
  const float* val_w   = (const float*)d_in[11];
  const float* val_b   = (const float*)d_in[12];
  const float* out_w   = (const float*)d_in[13];
  const float* out_b   = (const float*)d_in[14];
  const float* ln1_g   = (const float*)d_in[15];
  const float* ln1_b   = (const float*)d_in[16];
  const float* ln2_g   = (const float*)d_in[17];
  const float* ln2_b   = (const float*)d_in[18];
  const float* ffn_w1  = (const float*)d_in[19];
  const float* ffn_b1  = (const float*)d_in[20];
  const float* ffn_w2  = (const float*)d_in[21];
  const float* ffn_b2  = (const float*)d_in[22];

  char* p = (char*)d_ws;
  auto alloc = [&](size_t bytes) -> char* {
    char* r = p;
    p += (bytes + 255) & ~(size_t)255;
    return r;
  };
  const size_t valSlab = (size_t)kL * kNQ * kE;        // shorts per layer-val
  short* f_bf    = (short*)alloc((size_t)kL * kNQ * kC * 2);
  short* val_bf  = (short*)alloc(3 * valSlab * 2);     // 3 layer slabs
  float* q       = (float*)alloc((size_t)kNQ * kE * 4);
  short* accb    = (short*)alloc((size_t)kNQ * kE * 2);
  short* comb_bf = (short*)alloc((size_t)kNQ * 256 * 2);
  float* comb_b  = (float*)alloc((size_t)kNL * 256 * 4);
  short* inT     = (short*)alloc((size_t)256 * 1280 * 2);
  short* valT    = (short*)alloc((size_t)kNL * 256 * 256 * 2);
  short* outT    = (short*)alloc((size_t)kNL * 256 * 256 * 2);
  short* ffn1T   = (short*)alloc((size_t)kNL * 512 * 256 * 2);
  short* ffn2T   = (short*)alloc((size_t)kNL * 256 * 512 * 2);
  short* combT   = (short*)alloc((size_t)kNL * 256 * 256 * 2);

  // all weight conversions in one dispatch
  convert_all_kernel<<<12032, 256, 0, stream>>>(
      in_w, val_w, out_w, ffn_w1, ffn_w2, off_w, aw_w, off_b, aw_b,
      inT, valT, outT, ffn1T, ffn2T, combT, comb_b);

  // fused feature LN (stats + apply + transpose) -> f bf16
  ln_fused_kernel<<<dim3(kNQ / 32, kL), 256, 0, stream>>>(feat, norm0_g,
                                                          norm0_b, f_bf);

  const long zouts = (long)kL * kNQ * 256 - 256;   // val z-stride correction
  // val for layers 0..2, batched: grid (3, 1280)
  gemm2_kernel<64, 0, 0><<<dim3(3, kL * kNQ / 64), 512, 0, stream>>>(
      f_bf, 0, kC, valT, 256, 256, 1, val_b,
      nullptr, val_bf, kE, 0, zouts, nullptr, nullptr,
      nullptr, nullptr, nullptr);

  // input proj (K=1280) + pos epilogue -> q fp32; fused layer-0 comb GEMM
  gemm2_kernel<64, 5, 0><<<dim3(1, kNQ / 64), 512, 0, stream>>>(
      f_bf, (long)kNQ * kC, kC, inT, 1280, 256, kL, in_b,
      q, nullptr, 256, 0, 0, pos_row, pos_col, combT, comb_b, comb_bf);

  for (int i = 0; i < kNL; ++i) {
    const short* outT_i  = outT + (long)i * 256 * 256;
    const short* f1T_i   = ffn1T + (long)i * 512 * 256;
    const short* f2T_i   = ffn2T + (long)i * 256 * 512;

    // fused softmax + sampling (reads slab i%3)
    sample_kernel<<<kNQ / 8, 256, 0, stream>>>(
        (const unsigned short*)comb_bf, val_bf + (long)(i % 3) * valSlab,
        accb);
    if (i == 2) {
      // val for layers 3..5 into the (now free) 3 slabs
      gemm2_kernel<64, 0, 0><<<dim3(3, kL * kNQ / 64), 512, 0, stream>>>(
          f_bf, 0, kC, valT + 3 * 256 * 256, 256, 256, 1, val_b + 3 * kE,
          nullptr, val_bf, kE, 0, zouts, nullptr, nullptr,
          nullptr, nullptr, nullptr);
    }
    // full layer: out-proj+LN1+FFN(halved)+LN2 (+comb for i+1)
    if (i + 1 < kNL) {
      layer_kernel<0><<<dim3(1, kNQ / 64), 512, 0, stream>>>(
          accb, outT_i, out_b + (long)i * kE, q,
          ln1_g + (long)i * kE, ln1_b + (long)i * kE,
          f1T_i, ffn_b1 + (long)i * kFF,
          f2T_i, ffn_b2 + (long)i * kE,
          ln2_g + (long)i * kE, ln2_b + (long)i * kE,
          pos_row, pos_col,
          combT + (long)(i + 1) * 256 * 256, comb_b + (i + 1) * 256, comb_bf);
    } else {
      layer_kernel<1><<<dim3(1, kNQ / 64), 512, 0, stream>>>(
          accb, outT_i, out_b + (long)i * kE, q,
          ln1_g + (long)i * kE, ln1_b + (long)i * kE,
          f1T_i, ffn_b1 + (long)i * kFF,
          f2T_i, ffn_b2 + (long)i * kE,
          ln2_g + (long)i * kE, ln2_b + (long)i * kE,
          pos_row, pos_col, nullptr, nullptr, nullptr);
    }
  }

  transpose_kernel<<<dim3(kE / 32, kNQ / 32), 256, 0, stream>>>(q,
                                                                (float*)d_out);
}